// Round 6
// baseline (604.835 us; speedup 1.0000x reference)
//
#include <hip/hip_runtime.h>

// MTRNNCell on MI355X (gfx950). Inputs/outputs fp32 (proven R5: fp32-path
// out_head passed). Reference for compare is bf16-rounded; threshold 2e-2.
// ZERO d_ws usage (ws reads returned stale garbage in R2/R3 probes).
// Heads new_io/new_fast/new_slow: MFMA bf16 16x16x32, 128x128 tile, BK=64,
//   2x2 waves x 4x4 fragments (R5 bug: NI=2 left cols 64..127 unwritten ->
//   the exact absmax=1.0 = bf16(ref_max) vs memset-0 signature).
//   A: fp32 global -> regs -> bf16 -> ds_write_b128, XOR-swizzled chunks.
//   B: staged from original W[k][n], coalesced along n, 8 strided k per lane.
// Head `output`: VALU GEMM (passed R5, unchanged).

typedef unsigned short u16;
typedef unsigned int u32;
typedef unsigned long long u64;
typedef __attribute__((ext_vector_type(4))) unsigned short u16x4;
typedef __attribute__((ext_vector_type(8))) unsigned short u16x8;
typedef __attribute__((ext_vector_type(8))) __bf16 bf16x8;
typedef __attribute__((ext_vector_type(4))) float f32x4;

#define DI __device__ __forceinline__

DI float bf2f(u16 u) {
    union { u32 i; float f; } x; x.i = ((u32)u) << 16; return x.f;
}
DI u16 f2bf(float f) {  // fp32 -> bf16 round-to-nearest-even
    union { float f; u32 i; } x; x.f = f;
    u32 r = x.i + 0x7fffu + ((x.i >> 16) & 1u);
    return (u16)(r >> 16);
}

// true -> fp32 data, false -> bf16 (kept: proven in R5, costs ~nothing).
DI bool detect_f32(const void* probe) {
    const u32* p = (const u32*)probe;
    u32 w = p[threadIdx.x & 63];
    u32 lo = w & 0xffffu;
    u32 el = (lo >> 7) & 0xffu;
    bool sane = (el == 0) || (el >= 90 && el <= 150);
    u64 m = __ballot(sane);
    return __popcll(m) < 48;
}

DI float ldval(const void* p, size_t i, bool is32) {
    return is32 ? ((const float*)p)[i] : bf2f(((const u16*)p)[i]);
}
DI void stval(void* p, size_t i, bool is32, float v) {
    if (is32) ((float*)p)[i] = v; else ((u16*)p)[i] = f2bf(v);
}

DI bf16x8 loadA8(const void* p, size_t idx, bool is32) {  // 8 contiguous
    union { u16x8 u; bf16x8 b; } r;
    if (is32) {
        const float* f = (const float*)p + idx;
        float4 a = *(const float4*)f;
        float4 c = *(const float4*)(f + 4);
        r.u[0] = f2bf(a.x); r.u[1] = f2bf(a.y); r.u[2] = f2bf(a.z); r.u[3] = f2bf(a.w);
        r.u[4] = f2bf(c.x); r.u[5] = f2bf(c.y); r.u[6] = f2bf(c.z); r.u[7] = f2bf(c.w);
    } else {
        r.u = *(const u16x8*)((const u16*)p + idx);
    }
    return r.b;
}

DI bf16x8 loadB8(const void* p, size_t base, int stride, bool is32) {  // strided
    union { u16x8 u; bf16x8 b; } r;
    if (is32) {
        const float* f = (const float*)p;
        #pragma unroll
        for (int j = 0; j < 8; ++j) r.u[j] = f2bf(f[base + (size_t)j * stride]);
    } else {
        const u16* h = (const u16*)p;
        #pragma unroll
        for (int j = 0; j < 8; ++j) r.u[j] = h[base + (size_t)j * stride];
    }
    return r.b;
}

// ---------------------------------------------------------------- MFMA GEMM
struct Seg {
    const void* act;   // [BATCH][ld] activations, ld = segment K width
    const void* w;     // [ld][N] weights, row-major
    const void* bias;  // [N]
    int ld;
};

struct GroupDesc {
    Seg seg[3];
    int nseg;
    int kb[4];           // cumulative K boundaries (multiples of 64)
    const void* prev;    // [BATCH][N]
    void* out;           // d_out base
    size_t out_elem;     // element offset of this output region in d_out
    int Ktot, N;
    float a_keep, b_mix;
    int tile_base;
    int tilesN;          // N / 128
};

__global__ __launch_bounds__(256, 2)
void gemm_kernel(GroupDesc g0, GroupDesc g1, GroupDesc g2, const void* probe) {
    constexpr int MI = 4, NI = 4;   // 2x2 waves, each 64x64 -> full 128x128
    __shared__ __align__(16) u16 Alds[128 * 64];
    __shared__ __align__(16) u16 Blds[128 * 64];

    const bool is32 = detect_f32(probe);

    GroupDesc g = g0;
    const int bid = blockIdx.x;
    if (bid >= g2.tile_base) g = g2;
    else if (bid >= g1.tile_base) g = g1;
    const int tile = bid - g.tile_base;
    const int tm = tile / g.tilesN, tn = tile % g.tilesN;

    const int tid  = threadIdx.x;
    const int lane = tid & 63, wave = tid >> 6;
    const int wm = wave >> 1, wn = wave & 1;
    const int q = lane >> 4, l15 = lane & 15;

    f32x4 acc[MI][NI];
    #pragma unroll
    for (int i = 0; i < MI; ++i)
        #pragma unroll
        for (int j = 0; j < NI; ++j)
            acc[i][j] = (f32x4){0.f, 0.f, 0.f, 0.f};

    const int rowA0 = tm * 128;
    const int rowB0 = tn * 128;
    const int N = g.N;
    const int nKt = g.Ktot >> 6;

    for (int kt = 0; kt < nKt; ++kt) {
        const int k0 = kt << 6;
        int sidx = 0;
        while (sidx + 1 < g.nseg && k0 >= g.kb[sidx + 1]) ++sidx;
        const Seg sg = g.seg[sidx];
        const int ksg = k0 - g.kb[sidx];

        __syncthreads();   // previous iteration's LDS reads complete

        // A tile: 128 batch-rows x 64 k; chunk r=s>>3, c=s&7, store at c^(r&7)
        #pragma unroll
        for (int it = 0; it < 4; ++it) {
            int s = it * 256 + tid;
            int r = s >> 3, c = s & 7, cc = c ^ (r & 7);
            size_t gi = (size_t)(rowA0 + r) * sg.ld + ksg + c * 8;
            bf16x8 v = loadA8(sg.act, gi, is32);
            *(bf16x8*)&Alds[(size_t)r * 64 + cc * 8] = v;
        }
        // B tile: 128 n x 64 k from W[k][n]; n=tid&127 coalesced, c=it*2+(tid>>7)
        #pragma unroll
        for (int it = 0; it < 4; ++it) {
            int n = tid & 127;
            int c = it * 2 + (tid >> 7);
            int cc = c ^ (n & 7);
            size_t base = (size_t)(ksg + c * 8) * N + rowB0 + n;
            bf16x8 v = loadB8(sg.w, base, N, is32);
            *(bf16x8*)&Blds[(size_t)n * 64 + cc * 8] = v;
        }
        __syncthreads();

        #pragma unroll
        for (int ks = 0; ks < 2; ++ks) {
            bf16x8 af[MI], bfr[NI];
            #pragma unroll
            for (int i = 0; i < MI; ++i) {
                int m = wm * 64 + i * 16 + l15;
                af[i] = *(const bf16x8*)&Alds[m * 64 + (((ks << 2) | q) ^ (m & 7)) * 8];
            }
            #pragma unroll
            for (int j = 0; j < NI; ++j) {
                int n = wn * 64 + j * 16 + l15;
                bfr[j] = *(const bf16x8*)&Blds[n * 64 + (((ks << 2) | q) ^ (n & 7)) * 8];
            }
            #pragma unroll
            for (int i = 0; i < MI; ++i)
                #pragma unroll
                for (int j = 0; j < NI; ++j)
                    acc[i][j] = __builtin_amdgcn_mfma_f32_16x16x32_bf16(
                        af[i], bfr[j], acc[i][j], 0, 0, 0);
        }
    }

    // epilogue: out = tanh(a*prev + b*(acc+bias)); C/D: col=lane&15, row=q*4+reg
    const float a = g.a_keep, b = g.b_mix;
    #pragma unroll
    for (int j = 0; j < NI; ++j) {
        int gc = rowB0 + wn * 64 + j * 16 + l15;
        float bsum = 0.f;
        for (int t = 0; t < g.nseg; ++t) bsum += ldval(g.seg[t].bias, gc, is32);
        #pragma unroll
        for (int i = 0; i < MI; ++i) {
            int gr0 = rowA0 + wm * 64 + i * 16 + q * 4;
            #pragma unroll
            for (int r = 0; r < 4; ++r) {
                size_t off = (size_t)(gr0 + r) * N + gc;
                float v = acc[i][j][r] + bsum;
                float pv = ldval(g.prev, off, is32);
                stval(g.out, g.out_elem + off, is32, tanhf(fmaf(a, pv, b * v)));
            }
        }
    }
}

// ------------------------------------------------- output head (VALU)
__global__ __launch_bounds__(256) void out_head_kernel(const void* __restrict__ x,
                                                       const void* __restrict__ W,
                                                       const void* __restrict__ bias,
                                                       void* __restrict__ out,
                                                       const void* probe) {
    __shared__ float Wl[128 * 64];
    const bool is32 = detect_f32(probe);
    const int tid = threadIdx.x;
    const int wave = tid >> 6, lane = tid & 63;
    const int row0 = blockIdx.x * 16 + wave * 4;
    float acc0 = 0.f, acc1 = 0.f, acc2 = 0.f, acc3 = 0.f;

    for (int k0 = 0; k0 < 512; k0 += 128) {
        __syncthreads();
        #pragma unroll
        for (int i = 0; i < 4; ++i) {
            int idx = (i * 256 + tid) * 8;
            if (is32) {
                const float* f = (const float*)W + (size_t)k0 * 64 + idx;
                float4 a = *(const float4*)f;
                float4 c = *(const float4*)(f + 4);
                Wl[idx + 0] = a.x; Wl[idx + 1] = a.y; Wl[idx + 2] = a.z; Wl[idx + 3] = a.w;
                Wl[idx + 4] = c.x; Wl[idx + 5] = c.y; Wl[idx + 6] = c.z; Wl[idx + 7] = c.w;
            } else {
                u16x8 w = *(const u16x8*)((const u16*)W + (size_t)k0 * 64 + idx);
                #pragma unroll
                for (int e = 0; e < 8; ++e) Wl[idx + e] = bf2f(w[e]);
            }
        }
        __syncthreads();
        #pragma unroll 4
        for (int kk = 0; kk < 128; kk += 4) {
            float x0[4], x1[4], x2[4], x3[4];
            if (is32) {
                const float* f = (const float*)x;
                float4 v0 = *(const float4*)&f[(size_t)(row0 + 0) * 512 + k0 + kk];
                float4 v1 = *(const float4*)&f[(size_t)(row0 + 1) * 512 + k0 + kk];
                float4 v2 = *(const float4*)&f[(size_t)(row0 + 2) * 512 + k0 + kk];
                float4 v3 = *(const float4*)&f[(size_t)(row0 + 3) * 512 + k0 + kk];
                x0[0]=v0.x; x0[1]=v0.y; x0[2]=v0.z; x0[3]=v0.w;
                x1[0]=v1.x; x1[1]=v1.y; x1[2]=v1.z; x1[3]=v1.w;
                x2[0]=v2.x; x2[1]=v2.y; x2[2]=v2.z; x2[3]=v2.w;
                x3[0]=v3.x; x3[1]=v3.y; x3[2]=v3.z; x3[3]=v3.w;
            } else {
                const u16* h = (const u16*)x;
                u16x4 v0 = *(const u16x4*)&h[(size_t)(row0 + 0) * 512 + k0 + kk];
                u16x4 v1 = *(const u16x4*)&h[(size_t)(row0 + 1) * 512 + k0 + kk];
                u16x4 v2 = *(const u16x4*)&h[(size_t)(row0 + 2) * 512 + k0 + kk];
                u16x4 v3 = *(const u16x4*)&h[(size_t)(row0 + 3) * 512 + k0 + kk];
                #pragma unroll
                for (int e = 0; e < 4; ++e) {
                    x0[e] = bf2f(v0[e]); x1[e] = bf2f(v1[e]);
                    x2[e] = bf2f(v2[e]); x3[e] = bf2f(v3[e]);
                }
            }
            #pragma unroll
            for (int e = 0; e < 4; ++e) {
                float w = Wl[(kk + e) * 64 + lane];
                acc0 = fmaf(x0[e], w, acc0);
                acc1 = fmaf(x1[e], w, acc1);
                acc2 = fmaf(x2[e], w, acc2);
                acc3 = fmaf(x3[e], w, acc3);
            }
        }
    }
    const float bs = ldval(bias, lane, is32);
    stval(out, (size_t)(row0 + 0) * 64 + lane, is32, tanhf(acc0 + bs));
    stval(out, (size_t)(row0 + 1) * 64 + lane, is32, tanhf(acc1 + bs));
    stval(out, (size_t)(row0 + 2) * 64 + lane, is32, tanhf(acc2 + bs));
    stval(out, (size_t)(row0 + 3) * 64 + lane, is32, tanhf(acc3 + bs));
}

// ---------------------------------------------------------------- launch
extern "C" void kernel_launch(void* const* d_in, const int* in_sizes, int n_in,
                              void* d_out, int out_size, void* d_ws, size_t ws_size,
                              hipStream_t stream) {
    const void* input  = d_in[0];
    const void* io_h   = d_in[1];
    const void* fast_h = d_in[2];
    const void* slow_h = d_in[3];
    const void* W_in_io     = d_in[4];
    const void* b_in_io     = d_in[5];
    const void* W_io_fast   = d_in[6];
    const void* b_io_fast   = d_in[7];
    const void* W_fast_fast = d_in[8];
    const void* b_fast_fast = d_in[9];
    const void* W_fast_slow = d_in[10];
    const void* b_fast_slow = d_in[11];
    const void* W_slow_slow = d_in[12];
    const void* b_slow_slow = d_in[13];
    const void* W_slow_fast = d_in[14];
    const void* b_slow_fast = d_in[15];
    const void* W_fast_io   = d_in[16];
    const void* b_fast_io   = d_in[17];
    const void* W_io_io     = d_in[18];
    const void* b_io_io     = d_in[19];
    const void* W_io_out    = d_in[20];
    const void* b_io_out    = d_in[21];
    (void)d_ws; (void)ws_size; (void)in_sizes; (void)n_in; (void)out_size;

    GroupDesc g_io;
    g_io.seg[0] = {io_h,   W_io_io,   b_io_io,   512};
    g_io.seg[1] = {fast_h, W_fast_io, b_fast_io, 512};
    g_io.seg[2] = {input,  W_in_io,   b_in_io,    64};
    g_io.nseg = 3; g_io.kb[0] = 0; g_io.kb[1] = 512; g_io.kb[2] = 1024; g_io.kb[3] = 1088;
    g_io.prev = io_h; g_io.out = d_out; g_io.out_elem = 1048576;
    g_io.Ktot = 1088; g_io.N = 512;
    g_io.a_keep = 0.5f; g_io.b_mix = 0.5f;
    g_io.tile_base = 0; g_io.tilesN = 4;

    GroupDesc g_fast;
    g_fast.seg[0] = {fast_h, W_fast_fast, b_fast_fast, 512};
    g_fast.seg[1] = {slow_h, W_slow_fast, b_slow_fast, 256};
    g_fast.seg[2] = {io_h,   W_io_fast,   b_io_fast,   512};
    g_fast.nseg = 3; g_fast.kb[0] = 0; g_fast.kb[1] = 512; g_fast.kb[2] = 768; g_fast.kb[3] = 1280;
    g_fast.prev = fast_h; g_fast.out = d_out; g_fast.out_elem = 9437184;
    g_fast.Ktot = 1280; g_fast.N = 512;
    g_fast.a_keep = 0.8f; g_fast.b_mix = 0.2f;
    g_fast.tile_base = 512; g_fast.tilesN = 4;

    GroupDesc g_slow;
    g_slow.seg[0] = {slow_h, W_slow_slow, b_slow_slow, 256};
    g_slow.seg[1] = {fast_h, W_fast_slow, b_fast_slow, 512};
    g_slow.seg[2] = {nullptr, nullptr, nullptr, 0};
    g_slow.nseg = 2; g_slow.kb[0] = 0; g_slow.kb[1] = 256; g_slow.kb[2] = 768; g_slow.kb[3] = 768;
    g_slow.prev = slow_h; g_slow.out = d_out; g_slow.out_elem = 17825792;
    g_slow.Ktot = 768; g_slow.N = 256;
    g_slow.a_keep = (float)(1.0 - 1.0 / 70.0); g_slow.b_mix = (float)(1.0 / 70.0);
    g_slow.tile_base = 1024; g_slow.tilesN = 2;

    hipLaunchKernelGGL(gemm_kernel, dim3(1280), dim3(256), 0, stream,
                       g_io, g_fast, g_slow, input);
    hipLaunchKernelGGL(out_head_kernel, dim3(1024), dim3(256), 0, stream,
                       io_h, W_io_out, b_io_out, d_out, input);
}

// Round 7
// 372.911 us; speedup vs baseline: 1.6219x; 1.6219x over previous
//
#include <hip/hip_runtime.h>

// MTRNNCell on MI355X (gfx950). Inputs/outputs fp32 (proven R5/R6).
// R7: host-gated fast path (ws_size >= REQ):
//   prep kernel: fp32 activations -> bf16 in ws; fp32 weights -> bf16 W^T
//   packs; biases pre-summed fp32.
//   4 MFMA heads (m97 recipe): global_load_lds(16B) for BOTH A and B,
//   XOR-swizzled LDS, bf16 16x16x32 MFMA, fused leak+tanh fp32 epilogue.
// Fallback (ws too small): R6 kernels verbatim (passed, 604us).

typedef unsigned short u16;
typedef unsigned int u32;
typedef unsigned long long u64;
typedef __attribute__((ext_vector_type(4))) unsigned short u16x4;
typedef __attribute__((ext_vector_type(8))) unsigned short u16x8;
typedef __attribute__((ext_vector_type(8))) __bf16 bf16x8;
typedef __attribute__((ext_vector_type(4))) float f32x4;

#define DI __device__ __forceinline__

DI float bf2f(u16 u) {
    union { u32 i; float f; } x; x.i = ((u32)u) << 16; return x.f;
}
DI u16 f2bf(float f) {  // fp32 -> bf16 round-to-nearest-even
    union { float f; u32 i; } x; x.f = f;
    u32 r = x.i + 0x7fffu + ((x.i >> 16) & 1u);
    return (u16)(r >> 16);
}

#define GLDS16(gp, lp)                                                         \
    __builtin_amdgcn_global_load_lds(                                          \
        (const __attribute__((address_space(1))) void*)(gp),                   \
        (__attribute__((address_space(3))) void*)(lp), 16, 0, 0)

// ============================== FAST PATH ==================================
// ---- prep: activation convert + weight transpose/pack + bias sums
struct TDesc {
    const float* W;  // fi x fo row-major fp32
    int fi, fo;
    u16* dst;        // bf16 W^T pack: row n length ld, this W at col k0
    int ld, k0;
    int tj;          // tiles along fo
    int base;        // first tile id (prefix sum)
};
struct CDesc { const float* src; u16* dst; };

struct PrepParams {
    CDesc c[4];                // io_h, fast_h, slow_h, input
    TDesc t[9];
    const float* bias_src[9];
    float* biasF;              // [1344] = 512 io | 512 fast | 256 slow | 64 out
};

// grid: 10752 convert + 352 transpose + 6 bias = 11110
__global__ __launch_bounds__(256) void prep_kernel(PrepParams P) {
    __shared__ u16 tile[64][66];
    int bid = blockIdx.x;
    const int tid = threadIdx.x;

    if (bid < 10752) {   // activation fp32 -> bf16, 2048 elems/block
        int ci, local;
        if (bid < 4096)       { ci = 0; local = bid; }
        else if (bid < 8192)  { ci = 1; local = bid - 4096; }
        else if (bid < 10240) { ci = 2; local = bid - 8192; }
        else                  { ci = 3; local = bid - 10240; }
        const float* s = P.c[ci].src;
        u16* d = P.c[ci].dst;
        size_t i0 = ((size_t)local * 256 + tid) * 8;
        float4 a = *(const float4*)(s + i0);
        float4 b = *(const float4*)(s + i0 + 4);
        u16x8 o;
        o[0] = f2bf(a.x); o[1] = f2bf(a.y); o[2] = f2bf(a.z); o[3] = f2bf(a.w);
        o[4] = f2bf(b.x); o[5] = f2bf(b.y); o[6] = f2bf(b.z); o[7] = f2bf(b.w);
        *(u16x8*)(d + i0) = o;
        return;
    }
    bid -= 10752;

    if (bid < 352) {     // one 64x64 weight tile: load+cvt, transpose, store
        int di = 0;
        while (di < 8 && bid >= P.t[di + 1].base) ++di;
        TDesc d = P.t[di];
        int tl = bid - d.base;
        int ti = tl / d.tj, tj = tl % d.tj;
        int r0 = ti * 64, c0 = tj * 64;
        #pragma unroll
        for (int it = 0; it < 2; ++it) {
            int ch = it * 256 + tid;
            int lr = ch >> 3, lc = (ch & 7) * 8;
            const float* p = d.W + (size_t)(r0 + lr) * d.fo + c0 + lc;
            float4 a = *(const float4*)p;
            float4 b = *(const float4*)(p + 4);
            tile[lr][lc + 0] = f2bf(a.x); tile[lr][lc + 1] = f2bf(a.y);
            tile[lr][lc + 2] = f2bf(a.z); tile[lr][lc + 3] = f2bf(a.w);
            tile[lr][lc + 4] = f2bf(b.x); tile[lr][lc + 5] = f2bf(b.y);
            tile[lr][lc + 6] = f2bf(b.z); tile[lr][lc + 7] = f2bf(b.w);
        }
        __syncthreads();
        #pragma unroll
        for (int it = 0; it < 2; ++it) {
            int ch = it * 256 + tid;
            int on = ch >> 3, ok = (ch & 7) * 8;
            u16x8 o;
            #pragma unroll
            for (int e = 0; e < 8; ++e) o[e] = tile[ok + e][on];
            *(u16x8*)(d.dst + (size_t)(c0 + on) * d.ld + d.k0 + r0 + ok) = o;
        }
    } else {             // bias sums (fp32)
        int e = (bid - 352) * 256 + tid;
        if (e < 1344) {
            float v;
            if (e < 512) {
                v = P.bias_src[0][e] + P.bias_src[1][e] + P.bias_src[2][e];
            } else if (e < 1024) {
                int n = e - 512;
                v = P.bias_src[3][n] + P.bias_src[4][n] + P.bias_src[5][n];
            } else if (e < 1280) {
                int n = e - 1024;
                v = P.bias_src[6][n] + P.bias_src[7][n];
            } else {
                v = P.bias_src[8][e - 1280];
            }
            P.biasF[e] = v;
        }
    }
}

// ---- fast GEMM: GLDS both operands, bf16 LDS, fp32 epilogue
struct SegF { const u16* act; int ld; };

struct GroupF {
    SegF seg[3];
    int nseg;
    int kb[4];           // cumulative K boundaries (multiples of 64)
    const u16* Wt;       // [N][Ktot] bf16 W^T pack
    const float* bias;   // [N] fp32 pre-summed
    const float* prev;   // [BATCH][N] fp32 (a_keep=0 groups still need valid ptr)
    float* out;          // [BATCH][N] fp32
    int Ktot, N;
    float a_keep, b_mix;
    int tile_base;
    int tilesN;          // N / BN
};

template <int BN, int WAVES_M, int WAVES_N>
__global__ __launch_bounds__(256, 2)
void gemm_fast(GroupF g0, GroupF g1, GroupF g2) {
    constexpr int MI = 128 / (16 * WAVES_M);
    constexpr int NI = BN / (16 * WAVES_N);
    __shared__ __align__(16) u16 Alds[128 * 64];
    __shared__ __align__(16) u16 Blds[BN * 64];

    GroupF g = g0;
    const int bid = blockIdx.x;
    if (bid >= g2.tile_base) g = g2;
    else if (bid >= g1.tile_base) g = g1;
    const int tile = bid - g.tile_base;
    const int tm = tile / g.tilesN, tn = tile % g.tilesN;

    const int tid  = threadIdx.x;
    const int lane = tid & 63, wave = tid >> 6;
    const int wm = wave / WAVES_N, wn = wave % WAVES_N;
    const int q = lane >> 4, l15 = lane & 15;

    f32x4 acc[MI][NI];
    #pragma unroll
    for (int i = 0; i < MI; ++i)
        #pragma unroll
        for (int j = 0; j < NI; ++j)
            acc[i][j] = (f32x4){0.f, 0.f, 0.f, 0.f};

    const int rowA0 = tm * 128;
    const int rowB0 = tn * BN;
    const int nKt = g.Ktot >> 6;

    for (int kt = 0; kt < nKt; ++kt) {
        const int k0 = kt << 6;
        int sidx = 0;
        while (sidx + 1 < g.nseg && k0 >= g.kb[sidx + 1]) ++sidx;
        const u16* Ap = g.seg[sidx].act;
        const int ldA = g.seg[sidx].ld;
        const int ksg = k0 - g.kb[sidx];

        __syncthreads();   // previous iteration's LDS reads complete
        // A: 128 rows x 64 k, 16B async chunks; LDS[s*8] = chunk(r=s>>3, c=(s&7)^(r&7))
        #pragma unroll
        for (int it = 0; it < 4; ++it) {
            int s = it * 256 + tid;
            int r = s >> 3;
            int c = (s & 7) ^ (r & 7);
            const u16* gp = Ap + (size_t)(rowA0 + r) * ldA + ksg + c * 8;
            u16* lp = &Alds[(size_t)(it * 256 + wave * 64) * 8];  // wave-uniform base
            GLDS16(gp, lp);
        }
        // B: BN rows (n) x 64 k from W^T pack
        #pragma unroll
        for (int it = 0; it < BN / 32; ++it) {
            int s = it * 256 + tid;
            int r = s >> 3;
            int c = (s & 7) ^ (r & 7);
            const u16* gp = g.Wt + (size_t)(rowB0 + r) * g.Ktot + k0 + c * 8;
            u16* lp = &Blds[(size_t)(it * 256 + wave * 64) * 8];
            GLDS16(gp, lp);
        }
        __syncthreads();   // drains vmcnt -> staged data visible

        #pragma unroll
        for (int ks = 0; ks < 2; ++ks) {
            bf16x8 af[MI], bfr[NI];
            #pragma unroll
            for (int i = 0; i < MI; ++i) {
                int m = wm * (MI * 16) + i * 16 + l15;
                af[i] = *(const bf16x8*)&Alds[m * 64 + (((ks << 2) | q) ^ (m & 7)) * 8];
            }
            #pragma unroll
            for (int j = 0; j < NI; ++j) {
                int n = wn * (NI * 16) + j * 16 + l15;
                bfr[j] = *(const bf16x8*)&Blds[n * 64 + (((ks << 2) | q) ^ (n & 7)) * 8];
            }
            #pragma unroll
            for (int i = 0; i < MI; ++i)
                #pragma unroll
                for (int j = 0; j < NI; ++j)
                    acc[i][j] = __builtin_amdgcn_mfma_f32_16x16x32_bf16(
                        af[i], bfr[j], acc[i][j], 0, 0, 0);
        }
    }

    // epilogue: out = tanh(a*prev + b*(acc+bias)); C/D: col=lane&15, row=q*4+reg
    const float a = g.a_keep, b = g.b_mix;
    #pragma unroll
    for (int j = 0; j < NI; ++j) {
        int gc = rowB0 + wn * (NI * 16) + j * 16 + l15;
        float bsum = g.bias[gc];
        #pragma unroll
        for (int i = 0; i < MI; ++i) {
            int gr0 = rowA0 + wm * (MI * 16) + i * 16 + q * 4;
            #pragma unroll
            for (int r = 0; r < 4; ++r) {
                size_t off = (size_t)(gr0 + r) * g.N + gc;
                float v = acc[i][j][r] + bsum;
                float pv = g.prev[off];
                g.out[off] = tanhf(fmaf(a, pv, b * v));
            }
        }
    }
}

// ============================ FALLBACK (R6) ================================
DI bool detect_f32(const void* probe) {
    const u32* p = (const u32*)probe;
    u32 w = p[threadIdx.x & 63];
    u32 lo = w & 0xffffu;
    u32 el = (lo >> 7) & 0xffu;
    bool sane = (el == 0) || (el >= 90 && el <= 150);
    u64 m = __ballot(sane);
    return __popcll(m) < 48;
}
DI float ldval(const void* p, size_t i, bool is32) {
    return is32 ? ((const float*)p)[i] : bf2f(((const u16*)p)[i]);
}
DI void stval(void* p, size_t i, bool is32, float v) {
    if (is32) ((float*)p)[i] = v; else ((u16*)p)[i] = f2bf(v);
}
DI bf16x8 loadA8(const void* p, size_t idx, bool is32) {
    union { u16x8 u; bf16x8 b; } r;
    if (is32) {
        const float* f = (const float*)p + idx;
        float4 a = *(const float4*)f;
        float4 c = *(const float4*)(f + 4);
        r.u[0] = f2bf(a.x); r.u[1] = f2bf(a.y); r.u[2] = f2bf(a.z); r.u[3] = f2bf(a.w);
        r.u[4] = f2bf(c.x); r.u[5] = f2bf(c.y); r.u[6] = f2bf(c.z); r.u[7] = f2bf(c.w);
    } else {
        r.u = *(const u16x8*)((const u16*)p + idx);
    }
    return r.b;
}
DI bf16x8 loadB8(const void* p, size_t base, int stride, bool is32) {
    union { u16x8 u; bf16x8 b; } r;
    if (is32) {
        const float* f = (const float*)p;
        #pragma unroll
        for (int j = 0; j < 8; ++j) r.u[j] = f2bf(f[base + (size_t)j * stride]);
    } else {
        const u16* h = (const u16*)p;
        #pragma unroll
        for (int j = 0; j < 8; ++j) r.u[j] = h[base + (size_t)j * stride];
    }
    return r.b;
}

struct Seg { const void* act; const void* w; const void* bias; int ld; };
struct GroupDesc {
    Seg seg[3];
    int nseg;
    int kb[4];
    const void* prev;
    void* out;
    size_t out_elem;
    int Ktot, N;
    float a_keep, b_mix;
    int tile_base;
    int tilesN;
};

__global__ __launch_bounds__(256, 2)
void gemm_kernel(GroupDesc g0, GroupDesc g1, GroupDesc g2, const void* probe) {
    constexpr int MI = 4, NI = 4;
    __shared__ __align__(16) u16 Alds[128 * 64];
    __shared__ __align__(16) u16 Blds[128 * 64];

    const bool is32 = detect_f32(probe);

    GroupDesc g = g0;
    const int bid = blockIdx.x;
    if (bid >= g2.tile_base) g = g2;
    else if (bid >= g1.tile_base) g = g1;
    const int tile = bid - g.tile_base;
    const int tm = tile / g.tilesN, tn = tile % g.tilesN;

    const int tid  = threadIdx.x;
    const int lane = tid & 63, wave = tid >> 6;
    const int wm = wave >> 1, wn = wave & 1;
    const int q = lane >> 4, l15 = lane & 15;

    f32x4 acc[MI][NI];
    #pragma unroll
    for (int i = 0; i < MI; ++i)
        #pragma unroll
        for (int j = 0; j < NI; ++j)
            acc[i][j] = (f32x4){0.f, 0.f, 0.f, 0.f};

    const int rowA0 = tm * 128;
    const int rowB0 = tn * 128;
    const int N = g.N;
    const int nKt = g.Ktot >> 6;

    for (int kt = 0; kt < nKt; ++kt) {
        const int k0 = kt << 6;
        int sidx = 0;
        while (sidx + 1 < g.nseg && k0 >= g.kb[sidx + 1]) ++sidx;
        const Seg sg = g.seg[sidx];
        const int ksg = k0 - g.kb[sidx];

        __syncthreads();
        #pragma unroll
        for (int it = 0; it < 4; ++it) {
            int s = it * 256 + tid;
            int r = s >> 3, c = s & 7, cc = c ^ (r & 7);
            size_t gi = (size_t)(rowA0 + r) * sg.ld + ksg + c * 8;
            bf16x8 v = loadA8(sg.act, gi, is32);
            *(bf16x8*)&Alds[(size_t)r * 64 + cc * 8] = v;
        }
        #pragma unroll
        for (int it = 0; it < 4; ++it) {
            int n = tid & 127;
            int c = it * 2 + (tid >> 7);
            int cc = c ^ (n & 7);
            size_t base = (size_t)(ksg + c * 8) * N + rowB0 + n;
            bf16x8 v = loadB8(sg.w, base, N, is32);
            *(bf16x8*)&Blds[(size_t)n * 64 + cc * 8] = v;
        }
        __syncthreads();

        #pragma unroll
        for (int ks = 0; ks < 2; ++ks) {
            bf16x8 af[MI], bfr[NI];
            #pragma unroll
            for (int i = 0; i < MI; ++i) {
                int m = wm * 64 + i * 16 + l15;
                af[i] = *(const bf16x8*)&Alds[m * 64 + (((ks << 2) | q) ^ (m & 7)) * 8];
            }
            #pragma unroll
            for (int j = 0; j < NI; ++j) {
                int n = wn * 64 + j * 16 + l15;
                bfr[j] = *(const bf16x8*)&Blds[n * 64 + (((ks << 2) | q) ^ (n & 7)) * 8];
            }
            #pragma unroll
            for (int i = 0; i < MI; ++i)
                #pragma unroll
                for (int j = 0; j < NI; ++j)
                    acc[i][j] = __builtin_amdgcn_mfma_f32_16x16x32_bf16(
                        af[i], bfr[j], acc[i][j], 0, 0, 0);
        }
    }

    const float a = g.a_keep, b = g.b_mix;
    #pragma unroll
    for (int j = 0; j < NI; ++j) {
        int gc = rowB0 + wn * 64 + j * 16 + l15;
        float bsum = 0.f;
        for (int t = 0; t < g.nseg; ++t) bsum += ldval(g.seg[t].bias, gc, is32);
        #pragma unroll
        for (int i = 0; i < MI; ++i) {
            int gr0 = rowA0 + wm * 64 + i * 16 + q * 4;
            #pragma unroll
            for (int r = 0; r < 4; ++r) {
                size_t off = (size_t)(gr0 + r) * N + gc;
                float v = acc[i][j][r] + bsum;
                float pv = ldval(g.prev, off, is32);
                stval(g.out, g.out_elem + off, is32, tanhf(fmaf(a, pv, b * v)));
            }
        }
    }
}

__global__ __launch_bounds__(256) void out_head_kernel(const void* __restrict__ x,
                                                       const void* __restrict__ W,
                                                       const void* __restrict__ bias,
                                                       void* __restrict__ out,
                                                       const void* probe) {
    __shared__ float Wl[128 * 64];
    const bool is32 = detect_f32(probe);
    const int tid = threadIdx.x;
    const int wave = tid >> 6, lane = tid & 63;
    const int row0 = blockIdx.x * 16 + wave * 4;
    float acc0 = 0.f, acc1 = 0.f, acc2 = 0.f, acc3 = 0.f;

    for (int k0 = 0; k0 < 512; k0 += 128) {
        __syncthreads();
        #pragma unroll
        for (int i = 0; i < 4; ++i) {
            int idx = (i * 256 + tid) * 8;
            if (is32) {
                const float* f = (const float*)W + (size_t)k0 * 64 + idx;
                float4 a = *(const float4*)f;
                float4 c = *(const float4*)(f + 4);
                Wl[idx + 0] = a.x; Wl[idx + 1] = a.y; Wl[idx + 2] = a.z; Wl[idx + 3] = a.w;
                Wl[idx + 4] = c.x; Wl[idx + 5] = c.y; Wl[idx + 6] = c.z; Wl[idx + 7] = c.w;
            } else {
                u16x8 w = *(const u16x8*)((const u16*)W + (size_t)k0 * 64 + idx);
                #pragma unroll
                for (int e = 0; e < 8; ++e) Wl[idx + e] = bf2f(w[e]);
            }
        }
        __syncthreads();
        #pragma unroll 4
        for (int kk = 0; kk < 128; kk += 4) {
            float x0[4], x1[4], x2[4], x3[4];
            if (is32) {
                const float* f = (const float*)x;
                float4 v0 = *(const float4*)&f[(size_t)(row0 + 0) * 512 + k0 + kk];
                float4 v1 = *(const float4*)&f[(size_t)(row0 + 1) * 512 + k0 + kk];
                float4 v2 = *(const float4*)&f[(size_t)(row0 + 2) * 512 + k0 + kk];
                float4 v3 = *(const float4*)&f[(size_t)(row0 + 3) * 512 + k0 + kk];
                x0[0]=v0.x; x0[1]=v0.y; x0[2]=v0.z; x0[3]=v0.w;
                x1[0]=v1.x; x1[1]=v1.y; x1[2]=v1.z; x1[3]=v1.w;
                x2[0]=v2.x; x2[1]=v2.y; x2[2]=v2.z; x2[3]=v2.w;
                x3[0]=v3.x; x3[1]=v3.y; x3[2]=v3.z; x3[3]=v3.w;
            } else {
                const u16* h = (const u16*)x;
                u16x4 v0 = *(const u16x4*)&h[(size_t)(row0 + 0) * 512 + k0 + kk];
                u16x4 v1 = *(const u16x4*)&h[(size_t)(row0 + 1) * 512 + k0 + kk];
                u16x4 v2 = *(const u16x4*)&h[(size_t)(row0 + 2) * 512 + k0 + kk];
                u16x4 v3 = *(const u16x4*)&h[(size_t)(row0 + 3) * 512 + k0 + kk];
                #pragma unroll
                for (int e = 0; e < 4; ++e) {
                    x0[e] = bf2f(v0[e]); x1[e] = bf2f(v1[e]);
                    x2[e] = bf2f(v2[e]); x3[e] = bf2f(v3[e]);
                }
            }
            #pragma unroll
            for (int e = 0; e < 4; ++e) {
                float w = Wl[(kk + e) * 64 + lane];
                acc0 = fmaf(x0[e], w, acc0);
                acc1 = fmaf(x1[e], w, acc1);
                acc2 = fmaf(x2[e], w, acc2);
                acc3 = fmaf(x3[e], w, acc3);
            }
        }
    }
    const float bs = ldval(bias, lane, is32);
    stval(out, (size_t)(row0 + 0) * 64 + lane, is32, tanhf(acc0 + bs));
    stval(out, (size_t)(row0 + 1) * 64 + lane, is32, tanhf(acc1 + bs));
    stval(out, (size_t)(row0 + 2) * 64 + lane, is32, tanhf(acc2 + bs));
    stval(out, (size_t)(row0 + 3) * 64 + lane, is32, tanhf(acc3 + bs));
}

// ---------------------------------------------------------------- launch
extern "C" void kernel_launch(void* const* d_in, const int* in_sizes, int n_in,
                              void* d_out, int out_size, void* d_ws, size_t ws_size,
                              hipStream_t stream) {
    const float* input  = (const float*)d_in[0];
    const float* io_h   = (const float*)d_in[1];
    const float* fast_h = (const float*)d_in[2];
    const float* slow_h = (const float*)d_in[3];
    const float* W_in_io     = (const float*)d_in[4];
    const float* b_in_io     = (const float*)d_in[5];
    const float* W_io_fast   = (const float*)d_in[6];
    const float* b_io_fast   = (const float*)d_in[7];
    const float* W_fast_fast = (const float*)d_in[8];
    const float* b_fast_fast = (const float*)d_in[9];
    const float* W_fast_slow = (const float*)d_in[10];
    const float* b_fast_slow = (const float*)d_in[11];
    const float* W_slow_slow = (const float*)d_in[12];
    const float* b_slow_slow = (const float*)d_in[13];
    const float* W_slow_fast = (const float*)d_in[14];
    const float* b_slow_fast = (const float*)d_in[15];
    const float* W_fast_io   = (const float*)d_in[16];
    const float* b_fast_io   = (const float*)d_in[17];
    const float* W_io_io     = (const float*)d_in[18];
    const float* b_io_io     = (const float*)d_in[19];
    const float* W_io_out    = (const float*)d_in[20];
    const float* b_io_out    = (const float*)d_in[21];

    float* out0 = (float*)d_out;
    float* outI = out0 + 1048576;
    float* outF = out0 + 9437184;
    float* outS = out0 + 17825792;

    // ws layout (u16 units): activations bf16 | W^T packs | fp32 bias sums
    constexpr size_t REQ = 46929152;  // bytes
    if (ws_size >= REQ) {
        u16* ws16    = (u16*)d_ws;
        u16* actIO   = ws16;                  // 16384 x 512
        u16* actFast = ws16 + 8388608;        // 16384 x 512
        u16* actSlow = ws16 + 16777216;       // 16384 x 256
        u16* actIn   = ws16 + 20971520;       // 16384 x 64
        u16* Wt_io   = ws16 + 22020096;       // 512 x 1088
        u16* Wt_fast = ws16 + 22577152;       // 512 x 1280
        u16* Wt_slow = ws16 + 23232512;       // 256 x 768
        u16* Wt_out  = ws16 + 23429120;       // 64 x 512
        float* biasF = (float*)(ws16 + 23461888);

        PrepParams P;
        P.c[0] = {io_h,   actIO};
        P.c[1] = {fast_h, actFast};
        P.c[2] = {slow_h, actSlow};
        P.c[3] = {input,  actIn};
        P.t[0] = {W_io_io,     512, 512, Wt_io,   1088,    0, 8,   0};
        P.t[1] = {W_fast_io,   512, 512, Wt_io,   1088,  512, 8,  64};
        P.t[2] = {W_in_io,      64, 512, Wt_io,   1088, 1024, 8, 128};
        P.t[3] = {W_fast_fast, 512, 512, Wt_fast, 1280,    0, 8, 136};
        P.t[4] = {W_slow_fast, 256, 512, Wt_fast, 1280,  512, 8, 200};
        P.t[5] = {W_io_fast,   512, 512, Wt_fast, 1280,  768, 8, 232};
        P.t[6] = {W_slow_slow, 256, 256, Wt_slow,  768,    0, 4, 296};
        P.t[7] = {W_fast_slow, 512, 256, Wt_slow,  768,  256, 4, 312};
        P.t[8] = {W_io_out,    512,  64, Wt_out,   512,    0, 1, 344};
        P.bias_src[0] = b_io_io;     P.bias_src[1] = b_fast_io;   P.bias_src[2] = b_in_io;
        P.bias_src[3] = b_fast_fast; P.bias_src[4] = b_slow_fast; P.bias_src[5] = b_io_fast;
        P.bias_src[6] = b_slow_slow; P.bias_src[7] = b_fast_slow; P.bias_src[8] = b_io_out;
        P.biasF = biasF;

        GroupF g_io;
        g_io.seg[0] = {actIO, 512}; g_io.seg[1] = {actFast, 512}; g_io.seg[2] = {actIn, 64};
        g_io.nseg = 3; g_io.kb[0] = 0; g_io.kb[1] = 512; g_io.kb[2] = 1024; g_io.kb[3] = 1088;
        g_io.Wt = Wt_io; g_io.bias = biasF; g_io.prev = io_h; g_io.out = outI;
        g_io.Ktot = 1088; g_io.N = 512;
        g_io.a_keep = 0.5f; g_io.b_mix = 0.5f;
        g_io.tile_base = 0; g_io.tilesN = 4;

        GroupF g_fast;
        g_fast.seg[0] = {actFast, 512}; g_fast.seg[1] = {actSlow, 256}; g_fast.seg[2] = {actIO, 512};
        g_fast.nseg = 3; g_fast.kb[0] = 0; g_fast.kb[1] = 512; g_fast.kb[2] = 768; g_fast.kb[3] = 1280;
        g_fast.Wt = Wt_fast; g_fast.bias = biasF + 512; g_fast.prev = fast_h; g_fast.out = outF;
        g_fast.Ktot = 1280; g_fast.N = 512;
        g_fast.a_keep = 0.8f; g_fast.b_mix = 0.2f;
        g_fast.tile_base = 512; g_fast.tilesN = 4;

        GroupF g_slow;
        g_slow.seg[0] = {actSlow, 256}; g_slow.seg[1] = {actFast, 512}; g_slow.seg[2] = {nullptr, 0};
        g_slow.nseg = 2; g_slow.kb[0] = 0; g_slow.kb[1] = 256; g_slow.kb[2] = 768; g_slow.kb[3] = 768;
        g_slow.Wt = Wt_slow; g_slow.bias = biasF + 1024; g_slow.prev = slow_h; g_slow.out = outS;
        g_slow.Ktot = 768; g_slow.N = 256;
        g_slow.a_keep = (float)(1.0 - 1.0 / 70.0); g_slow.b_mix = (float)(1.0 / 70.0);
        g_slow.tile_base = 1024; g_slow.tilesN = 2;

        GroupF g_out;
        g_out.seg[0] = {actIO, 512}; g_out.seg[1] = {nullptr, 0}; g_out.seg[2] = {nullptr, 0};
        g_out.nseg = 1; g_out.kb[0] = 0; g_out.kb[1] = 512; g_out.kb[2] = 512; g_out.kb[3] = 512;
        g_out.Wt = Wt_out; g_out.bias = biasF + 1280; g_out.prev = input;  // a=0: unused value
        g_out.out = out0; g_out.Ktot = 512; g_out.N = 64;
        g_out.a_keep = 0.0f; g_out.b_mix = 1.0f;
        g_out.tile_base = 0; g_out.tilesN = 1;

        hipLaunchKernelGGL(prep_kernel, dim3(11110), dim3(256), 0, stream, P);
        hipLaunchKernelGGL((gemm_fast<128, 2, 2>), dim3(1280), dim3(256), 0, stream,
                           g_io, g_fast, g_slow);
        hipLaunchKernelGGL((gemm_fast<64, 4, 1>), dim3(128), dim3(256), 0, stream,
                           g_out, g_out, g_out);
        return;
    }

    // ---------------- fallback: R6 verbatim ----------------
    GroupDesc f_io;
    f_io.seg[0] = {io_h,   W_io_io,   b_io_io,   512};
    f_io.seg[1] = {fast_h, W_fast_io, b_fast_io, 512};
    f_io.seg[2] = {input,  W_in_io,   b_in_io,    64};
    f_io.nseg = 3; f_io.kb[0] = 0; f_io.kb[1] = 512; f_io.kb[2] = 1024; f_io.kb[3] = 1088;
    f_io.prev = io_h; f_io.out = d_out; f_io.out_elem = 1048576;
    f_io.Ktot = 1088; f_io.N = 512;
    f_io.a_keep = 0.5f; f_io.b_mix = 0.5f;
    f_io.tile_base = 0; f_io.tilesN = 4;

    GroupDesc f_fast;
    f_fast.seg[0] = {fast_h, W_fast_fast, b_fast_fast, 512};
    f_fast.seg[1] = {slow_h, W_slow_fast, b_slow_fast, 256};
    f_fast.seg[2] = {io_h,   W_io_fast,   b_io_fast,   512};
    f_fast.nseg = 3; f_fast.kb[0] = 0; f_fast.kb[1] = 512; f_fast.kb[2] = 768; f_fast.kb[3] = 1280;
    f_fast.prev = fast_h; f_fast.out = d_out; f_fast.out_elem = 9437184;
    f_fast.Ktot = 1280; f_fast.N = 512;
    f_fast.a_keep = 0.8f; f_fast.b_mix = 0.2f;
    f_fast.tile_base = 512; f_fast.tilesN = 4;

    GroupDesc f_slow;
    f_slow.seg[0] = {slow_h, W_slow_slow, b_slow_slow, 256};
    f_slow.seg[1] = {fast_h, W_fast_slow, b_fast_slow, 512};
    f_slow.seg[2] = {nullptr, nullptr, nullptr, 0};
    f_slow.nseg = 2; f_slow.kb[0] = 0; f_slow.kb[1] = 256; f_slow.kb[2] = 768; f_slow.kb[3] = 768;
    f_slow.prev = slow_h; f_slow.out = d_out; f_slow.out_elem = 17825792;
    f_slow.Ktot = 768; f_slow.N = 256;
    f_slow.a_keep = (float)(1.0 - 1.0 / 70.0); f_slow.b_mix = (float)(1.0 / 70.0);
    f_slow.tile_base = 1024; f_slow.tilesN = 2;

    hipLaunchKernelGGL(gemm_kernel, dim3(1280), dim3(256), 0, stream,
                       f_io, f_fast, f_slow, input);
    hipLaunchKernelGGL(out_head_kernel, dim3(1024), dim3(256), 0, stream,
                       io_h, W_io_out, b_io_out, d_out, input);
}